// Round 2
// baseline (1026.613 us; speedup 1.0000x reference)
//
#include <hip/hip_runtime.h>
#include <hip/hip_bf16.h>

typedef unsigned int u32;
typedef unsigned short u16;

#define DIM 128

__device__ __forceinline__ float2 bfpair(u32 u) {
    union { u32 i; float f; } lo, hi;
    lo.i = (u & 0xFFFFu) << 16;
    hi.i = u & 0xFFFF0000u;
    return make_float2(lo.f, hi.f);
}
__device__ __forceinline__ float bf1(u16 h) {
    union { u32 i; float f; } a; a.i = ((u32)h) << 16; return a.f;
}
__device__ __forceinline__ u16 f2bf(float f) {
    __hip_bfloat16 h = __float2bfloat16(f);   // RNE
    return *reinterpret_cast<u16*>(&h);
}
__device__ __forceinline__ u32 packbf(float x, float y) {
    return (u32)f2bf(x) | ((u32)f2bf(y) << 16);
}

// scalar "float input" load, dtype-aware
template<bool BF16>
__device__ __forceinline__ float ldf(const void* p, int i) {
    if constexpr (BF16) return bf1(((const u16*)p)[i]);
    else                return ((const float*)p)[i];
}

// ---------------------------------------------------------------------------
// Sniffer: decide (a) are float tensors bf16 or fp32, (b) is edge_index int64.
// flags[0] = 1 if bf16, flags[1] = 1 if int64 layout.
// ---------------------------------------------------------------------------
__global__ __launch_bounds__(64) void sniff_kernel(const u32* __restrict__ x0w,
                                                   const int* __restrict__ eiw,
                                                   int* __restrict__ flags) {
    int l = threadIdx.x;
    u32 w = x0w[l];
    u32 ef = (w >> 7) & 0xFF;                 // exponent field of low halfword if bf16
    bool inr = (ef >= 99 && ef <= 141);       // |v| in [2^-28, 2^14]
    unsigned long long m1 = __ballot(inr);
    bool zodd = (eiw[2 * l + 1] == 0);        // high words zero if int64
    unsigned long long m2 = __ballot(zodd);
    if (l == 0) {
        flags[0] = (__popcll(m1) >= 48) ? 1 : 0;
        flags[1] = (__popcll(m2) >= 32) ? 1 : 0;
    }
}

// ---------------------------------------------------------------------------
// Projection: 32 rows/block, thread c owns output column c. W rows packed
// bf16 in VGPRs (fp32 mode: converted on load — 0.4% rel err << 2% tol).
// Emits x0_j (bf16, ws), a1/a2 (fp32, ws).
// ---------------------------------------------------------------------------
template<bool BF16>
__global__ __launch_bounds__(128) void proj_kernel(
    const void* __restrict__ x0v,
    const void* __restrict__ W1v, const void* __restrict__ b1v,
    const void* __restrict__ W2v, const void* __restrict__ b2v,
    const void* __restrict__ a1wv, const void* __restrict__ a1bv,
    const void* __restrict__ a2wv, const void* __restrict__ a2bv,
    u16* __restrict__ xj, float* __restrict__ a1, float* __restrict__ a2,
    const int* __restrict__ flags, int n)
{
    if ((flags[0] != 0) != BF16) return;      // not our dtype: ghost launch

    __shared__ float xs[32][DIM];
    __shared__ float red1[2][32];
    __shared__ float red2[2][32];

    const int c  = threadIdx.x;
    const int r0 = blockIdx.x * 32;
    const int rows = min(32, n - r0);

    u32 w1r[64], w2r[64];
    if constexpr (BF16) {
        const u32* p1 = (const u32*)W1v + (size_t)c * 64;
        const u32* p2 = (const u32*)W2v + (size_t)c * 64;
        #pragma unroll
        for (int i = 0; i < 64; ++i) { w1r[i] = p1[i]; w2r[i] = p2[i]; }
    } else {
        const float2* p1 = (const float2*)W1v + (size_t)c * 64;
        const float2* p2 = (const float2*)W2v + (size_t)c * 64;
        #pragma unroll
        for (int i = 0; i < 64; ++i) {
            float2 v1 = p1[i], v2 = p2[i];
            w1r[i] = packbf(v1.x, v1.y);
            w2r[i] = packbf(v2.x, v2.y);
        }
    }

    if constexpr (BF16) {
        const u32* xp = (const u32*)x0v + (size_t)r0 * 64;
        int npairs = rows * 64;
        for (int j = c; j < npairs; j += 128) {
            float2 v = bfpair(xp[j]);
            int rr = j >> 6, cp = (j & 63) * 2;
            xs[rr][cp] = v.x; xs[rr][cp + 1] = v.y;
        }
    } else {
        const float* xp = (const float*)x0v + (size_t)r0 * DIM;
        int nel = rows * DIM;
        for (int j = c; j < nel; j += 128) xs[j >> 7][j & 127] = xp[j];
    }
    __syncthreads();

    const float b1c = ldf<BF16>(b1v, c), b2c = ldf<BF16>(b2v, c);
    const float a1wc = ldf<BF16>(a1wv, c), a2wc = ldf<BF16>(a2wv, c);
    const int wv = c >> 6;

    for (int r = 0; r < rows; ++r) {
        float acc1 = b1c, acc2 = b2c;
        const float2* xr = reinterpret_cast<const float2*>(xs[r]);
        #pragma unroll
        for (int i = 0; i < 64; ++i) {
            float2 xv  = xr[i];
            float2 w1v = bfpair(w1r[i]);
            float2 w2v = bfpair(w2r[i]);
            acc1 = fmaf(xv.x, w1v.x, fmaf(xv.y, w1v.y, acc1));
            acc2 = fmaf(xv.x, w2v.x, fmaf(xv.y, w2v.y, acc2));
        }
        float v1 = acc1 >= 0.f ? acc1 : 0.2f * acc1;   // LeakyReLU(0.2)
        float v2 = acc2 >= 0.f ? acc2 : 0.2f * acc2;
        xj[(size_t)(r0 + r) * DIM + c] = f2bf(v2);
        float p1 = v1 * a1wc, p2 = v2 * a2wc;
        #pragma unroll
        for (int off = 32; off > 0; off >>= 1) {
            p1 += __shfl_down(p1, off);
            p2 += __shfl_down(p2, off);
        }
        if ((c & 63) == 0) { red1[wv][r] = p1; red2[wv][r] = p2; }
    }
    __syncthreads();
    if (c < rows) {
        a1[r0 + c] = red1[0][c] + red1[1][c] + ldf<BF16>(a1bv, 0);
        a2[r0 + c] = red2[0][c] + red2[1][c] + ldf<BF16>(a2bv, 0);
    }
}

// ---------------------------------------------------------------------------
// Edge scatter: one wave per edge, lane l covers cols 2l,2l+1. fp32 atomics.
// ---------------------------------------------------------------------------
__global__ __launch_bounds__(256) void edge_kernel(
    const int* __restrict__ ei, const u16* __restrict__ xj,
    const float* __restrict__ a1, const float* __restrict__ a2,
    float* __restrict__ acc, const int* __restrict__ flags, int ne)
{
    long long gid = (long long)blockIdx.x * 256 + threadIdx.x;
    int e = (int)(gid >> 6);
    int l = (int)(gid & 63);
    if (e >= ne) return;
    int src, dst;
    if (flags[1]) { src = ei[2 * e]; dst = ei[2 * (ne + e)]; }   // int64 layout
    else          { src = ei[e];     dst = ei[ne + e];       }   // int32 layout
    float av  = a1[src] + a2[dst];
    float att = 1.0f / (1.0f + __expf(-av));
    u32 xp = reinterpret_cast<const u32*>(xj + (size_t)dst * DIM)[l];
    float2 xv = bfpair(xp);
    float* base = acc + (size_t)src * DIM + 2 * l;
    atomicAdd(base,     att * xv.x);
    atomicAdd(base + 1, att * xv.y);
}

// ---------------------------------------------------------------------------
// Epilogue: out = (acc + x0), dtype-aware.
// ---------------------------------------------------------------------------
template<bool BF16>
__global__ __launch_bounds__(256) void final_kernel(
    const float* __restrict__ acc, const void* __restrict__ x0v,
    void* __restrict__ outv, const int* __restrict__ flags, int total)
{
    if ((flags[0] != 0) != BF16) return;
    int i = blockIdx.x * 256 + threadIdx.x;   // one pair of elements
    int j = i * 2;
    if (j >= total) return;
    float2 av = *reinterpret_cast<const float2*>(acc + j);
    if constexpr (BF16) {
        float2 xv = bfpair(((const u32*)x0v)[i]);
        ((u32*)outv)[i] = packbf(av.x + xv.x, av.y + xv.y);
    } else {
        float2 xv = ((const float2*)x0v)[i];
        float2 o; o.x = av.x + xv.x; o.y = av.y + xv.y;
        ((float2*)outv)[i] = o;
    }
}

extern "C" void kernel_launch(void* const* d_in, const int* in_sizes, int n_in,
                              void* d_out, int out_size, void* d_ws, size_t ws_size,
                              hipStream_t stream)
{
    const void* x0  = d_in[0];
    /* d_in[1] = x1: unused by the reference computation */
    const int*  ei  = (const int*)d_in[2];
    const void* W1  = d_in[3];
    const void* b1  = d_in[4];
    const void* W2  = d_in[5];
    const void* b2  = d_in[6];
    const void* a1w = d_in[7];
    const void* a1b = d_in[8];
    const void* a2w = d_in[9];
    const void* a2b = d_in[10];

    const int n = in_sizes[0] / DIM;        // 50000
    const int e = in_sizes[2] / 2;          // 800000

    // workspace layout: flags | acc fp32 | xj bf16 | a1 | a2
    char* ws = (char*)d_ws;
    int* flags = (int*)ws;
    size_t off = 256;
    float* acc = (float*)(ws + off);
    off += (size_t)n * DIM * sizeof(float);
    off = (off + 255) & ~(size_t)255;
    u16* xj = (u16*)(ws + off);
    off += (size_t)n * DIM * sizeof(u16);
    off = (off + 255) & ~(size_t)255;
    float* a1 = (float*)(ws + off);
    off += (size_t)n * sizeof(float);
    off = (off + 255) & ~(size_t)255;
    float* a2 = (float*)(ws + off);

    hipMemsetAsync(acc, 0, (size_t)n * DIM * sizeof(float), stream);

    sniff_kernel<<<1, 64, 0, stream>>>((const u32*)x0, ei, flags);

    int pblocks = (n + 31) / 32;
    proj_kernel<true ><<<pblocks, 128, 0, stream>>>(x0, W1, b1, W2, b2, a1w, a1b, a2w, a2b, xj, a1, a2, flags, n);
    proj_kernel<false><<<pblocks, 128, 0, stream>>>(x0, W1, b1, W2, b2, a1w, a1b, a2w, a2b, xj, a1, a2, flags, n);

    long long tot = (long long)e * 64;
    int eblocks = (int)((tot + 255) / 256);
    edge_kernel<<<eblocks, 256, 0, stream>>>(ei, xj, a1, a2, acc, flags, e);

    int total = n * DIM;
    int fblocks = (total / 2 + 255) / 256;
    final_kernel<true ><<<fblocks, 256, 0, stream>>>(acc, x0, d_out, flags, total);
    final_kernel<false><<<fblocks, 256, 0, stream>>>(acc, x0, d_out, flags, total);
}

// Round 3
// 409.366 us; speedup vs baseline: 2.5078x; 2.5078x over previous
//
#include <hip/hip_runtime.h>
#include <hip/hip_bf16.h>

typedef unsigned int u32;
typedef unsigned short u16;

#define DIM 128

__device__ __forceinline__ float2 bfpair(u32 u) {
    union { u32 i; float f; } lo, hi;
    lo.i = (u & 0xFFFFu) << 16;
    hi.i = u & 0xFFFF0000u;
    return make_float2(lo.f, hi.f);
}
__device__ __forceinline__ float bf1(u16 h) {
    union { u32 i; float f; } a; a.i = ((u32)h) << 16; return a.f;
}
__device__ __forceinline__ u16 f2bf(float f) {
    __hip_bfloat16 h = __float2bfloat16(f);   // RNE
    return *reinterpret_cast<u16*>(&h);
}
__device__ __forceinline__ u32 packbf(float x, float y) {
    return (u32)f2bf(x) | ((u32)f2bf(y) << 16);
}
// packed bf16 atomic add: one atomic covers two adjacent bf16 elements
__device__ __forceinline__ void atom_pk_add_bf16(u32* addr, u32 val) {
    asm volatile("global_atomic_pk_add_bf16 %0, %1, off" :: "v"(addr), "v"(val) : "memory");
}

template<bool BF16>
__device__ __forceinline__ float ldf(const void* p, int i) {
    if constexpr (BF16) return bf1(((const u16*)p)[i]);
    else                return ((const float*)p)[i];
}

// ---------------------------------------------------------------------------
// Sniffer: flags[0]=1 if float tensors are bf16; flags[1]=1 if edge_index int64.
// ---------------------------------------------------------------------------
__global__ __launch_bounds__(64) void sniff_kernel(const u32* __restrict__ x0w,
                                                   const int* __restrict__ eiw,
                                                   int* __restrict__ flags) {
    int l = threadIdx.x;
    u32 w = x0w[l];
    u32 ef = (w >> 7) & 0xFF;
    bool inr = (ef >= 99 && ef <= 141);
    unsigned long long m1 = __ballot(inr);
    bool zodd = (eiw[2 * l + 1] == 0);
    unsigned long long m2 = __ballot(zodd);
    if (l == 0) {
        flags[0] = (__popcll(m1) >= 48) ? 1 : 0;
        flags[1] = (__popcll(m2) >= 32) ? 1 : 0;
    }
}

// ---------------------------------------------------------------------------
// Projection: 256 threads/block, 32 rows/block. Thread t: group g=t>>7
// (g=0 -> W1/a1, g=1 -> W2/a2), column c=t&127. 64 packed-bf16 W regs per
// thread (half of round-2's 128 -> better occupancy, half the serial FMAs).
// ---------------------------------------------------------------------------
template<bool BF16>
__global__ __launch_bounds__(256) void proj_kernel(
    const void* __restrict__ x0v,
    const void* __restrict__ W1v, const void* __restrict__ b1v,
    const void* __restrict__ W2v, const void* __restrict__ b2v,
    const void* __restrict__ a1wv, const void* __restrict__ a1bv,
    const void* __restrict__ a2wv, const void* __restrict__ a2bv,
    u16* __restrict__ xj, float* __restrict__ a1, float* __restrict__ a2,
    const int* __restrict__ flags, int n)
{
    if ((flags[0] != 0) != BF16) return;      // not our dtype: ghost launch

    __shared__ float xs[32][DIM];
    __shared__ float red[2][2][32];

    const int t   = threadIdx.x;
    const int c   = t & 127;
    const int grp = t >> 7;                   // 0: W1 path, 1: W2 path
    const int r0  = blockIdx.x * 32;
    const int rows = min(32, n - r0);

    const void* Wv  = grp ? W2v  : W1v;
    const void* bv  = grp ? b2v  : b1v;
    const void* awv = grp ? a2wv : a1wv;

    u32 wr[64];
    if constexpr (BF16) {
        const u32* p = (const u32*)Wv + (size_t)c * 64;
        #pragma unroll
        for (int i = 0; i < 64; ++i) wr[i] = p[i];
    } else {
        const float2* p = (const float2*)Wv + (size_t)c * 64;
        #pragma unroll
        for (int i = 0; i < 64; ++i) { float2 v = p[i]; wr[i] = packbf(v.x, v.y); }
    }

    if constexpr (BF16) {
        const u32* xp = (const u32*)x0v + (size_t)r0 * 64;
        int npairs = rows * 64;
        for (int j = t; j < npairs; j += 256) {
            float2 v = bfpair(xp[j]);
            int rr = j >> 6, cp = (j & 63) * 2;
            xs[rr][cp] = v.x; xs[rr][cp + 1] = v.y;
        }
    } else {
        const float* xp = (const float*)x0v + (size_t)r0 * DIM;
        int nel = rows * DIM;
        for (int j = t; j < nel; j += 256) xs[j >> 7][j & 127] = xp[j];
    }
    __syncthreads();

    const float bc  = ldf<BF16>(bv, c);
    const float awc = ldf<BF16>(awv, c);
    const int wv_ = (t >> 6) & 1;             // wave within group

    for (int r = 0; r < rows; ++r) {
        float acc = bc;
        const float2* xr = reinterpret_cast<const float2*>(xs[r]);
        #pragma unroll
        for (int i = 0; i < 64; ++i) {
            float2 xv = xr[i];
            float2 wv2 = bfpair(wr[i]);
            acc = fmaf(xv.x, wv2.x, fmaf(xv.y, wv2.y, acc));
        }
        float v = acc >= 0.f ? acc : 0.2f * acc;   // LeakyReLU(0.2)
        if (grp) xj[(size_t)(r0 + r) * DIM + c] = f2bf(v);
        float p = v * awc;
        #pragma unroll
        for (int off = 32; off > 0; off >>= 1) p += __shfl_down(p, off);
        if ((t & 63) == 0) red[grp][wv_][r] = p;
    }
    __syncthreads();
    if (t < rows)
        a1[r0 + t] = red[0][0][t] + red[0][1][t] + ldf<BF16>(a1bv, 0);
    else if (t >= 128 && t - 128 < rows)
        a2[r0 + t - 128] = red[1][0][t - 128] + red[1][1][t - 128] + ldf<BF16>(a2bv, 0);
}

// ---------------------------------------------------------------------------
// Edge scatter: one wave per edge, lane l covers cols 2l,2l+1.
// ONE packed-bf16 atomic per lane (64/edge instead of 128 fp32 atomics).
// ---------------------------------------------------------------------------
__global__ __launch_bounds__(256) void edge_kernel(
    const int* __restrict__ ei, const u16* __restrict__ xj,
    const float* __restrict__ a1, const float* __restrict__ a2,
    u32* __restrict__ acc, const int* __restrict__ flags, int ne)
{
    long long gid = (long long)blockIdx.x * 256 + threadIdx.x;
    int e = (int)(gid >> 6);
    int l = (int)(gid & 63);
    if (e >= ne) return;
    int src, dst;
    if (flags[1]) { src = ei[2 * e]; dst = ei[2 * (ne + e)]; }   // int64 layout
    else          { src = ei[e];     dst = ei[ne + e];       }   // int32 layout
    float av  = a1[src] + a2[dst];
    float att = 1.0f / (1.0f + __expf(-av));
    u32 xp = reinterpret_cast<const u32*>(xj + (size_t)dst * DIM)[l];
    float2 xv = bfpair(xp);
    u32 msg = packbf(att * xv.x, att * xv.y);
    atom_pk_add_bf16(acc + (size_t)src * 64 + l, msg);
}

// ---------------------------------------------------------------------------
// Epilogue: out = (acc + x0), dtype-aware. acc is packed bf16 pairs.
// ---------------------------------------------------------------------------
template<bool BF16>
__global__ __launch_bounds__(256) void final_kernel(
    const u32* __restrict__ acc, const void* __restrict__ x0v,
    void* __restrict__ outv, const int* __restrict__ flags, int total)
{
    if ((flags[0] != 0) != BF16) return;
    int i = blockIdx.x * 256 + threadIdx.x;   // one pair of elements
    int j = i * 2;
    if (j >= total) return;
    float2 av = bfpair(acc[i]);
    if constexpr (BF16) {
        float2 xv = bfpair(((const u32*)x0v)[i]);
        ((u32*)outv)[i] = packbf(av.x + xv.x, av.y + xv.y);
    } else {
        float2 xv = ((const float2*)x0v)[i];
        float2 o; o.x = av.x + xv.x; o.y = av.y + xv.y;
        ((float2*)outv)[i] = o;
    }
}

extern "C" void kernel_launch(void* const* d_in, const int* in_sizes, int n_in,
                              void* d_out, int out_size, void* d_ws, size_t ws_size,
                              hipStream_t stream)
{
    const void* x0  = d_in[0];
    /* d_in[1] = x1: unused by the reference computation */
    const int*  ei  = (const int*)d_in[2];
    const void* W1  = d_in[3];
    const void* b1  = d_in[4];
    const void* W2  = d_in[5];
    const void* b2  = d_in[6];
    const void* a1w = d_in[7];
    const void* a1b = d_in[8];
    const void* a2w = d_in[9];
    const void* a2b = d_in[10];

    const int n = in_sizes[0] / DIM;        // 50000
    const int e = in_sizes[2] / 2;          // 800000

    // workspace layout: flags | acc (bf16 pairs) | xj bf16 | a1 | a2
    char* ws = (char*)d_ws;
    int* flags = (int*)ws;
    size_t off = 256;
    u32* acc = (u32*)(ws + off);                       // n*64 u32 (bf16 pairs)
    off += (size_t)n * 64 * sizeof(u32);
    off = (off + 255) & ~(size_t)255;
    u16* xj = (u16*)(ws + off);
    off += (size_t)n * DIM * sizeof(u16);
    off = (off + 255) & ~(size_t)255;
    float* a1 = (float*)(ws + off);
    off += (size_t)n * sizeof(float);
    off = (off + 255) & ~(size_t)255;
    float* a2 = (float*)(ws + off);

    hipMemsetAsync(acc, 0, (size_t)n * 64 * sizeof(u32), stream);

    sniff_kernel<<<1, 64, 0, stream>>>((const u32*)x0, ei, flags);

    int pblocks = (n + 31) / 32;
    proj_kernel<true ><<<pblocks, 256, 0, stream>>>(x0, W1, b1, W2, b2, a1w, a1b, a2w, a2b, xj, a1, a2, flags, n);
    proj_kernel<false><<<pblocks, 256, 0, stream>>>(x0, W1, b1, W2, b2, a1w, a1b, a2w, a2b, xj, a1, a2, flags, n);

    long long tot = (long long)e * 64;
    int eblocks = (int)((tot + 255) / 256);
    edge_kernel<<<eblocks, 256, 0, stream>>>(ei, xj, a1, a2, acc, flags, e);

    int total = n * DIM;
    int fblocks = (total / 2 + 255) / 256;
    final_kernel<true ><<<fblocks, 256, 0, stream>>>(acc, x0, d_out, flags, total);
    final_kernel<false><<<fblocks, 256, 0, stream>>>(acc, x0, d_out, flags, total);
}

// Round 4
// 405.719 us; speedup vs baseline: 2.5304x; 1.0090x over previous
//
#include <hip/hip_runtime.h>
#include <hip/hip_bf16.h>

typedef unsigned int u32;
typedef unsigned short u16;

#define DIM 128

__device__ __forceinline__ float2 bfpair(u32 u) {
    union { u32 i; float f; } lo, hi;
    lo.i = (u & 0xFFFFu) << 16;
    hi.i = u & 0xFFFF0000u;
    return make_float2(lo.f, hi.f);
}
__device__ __forceinline__ float bf1(u16 h) {
    union { u32 i; float f; } a; a.i = ((u32)h) << 16; return a.f;
}
__device__ __forceinline__ u16 f2bf(float f) {
    __hip_bfloat16 h = __float2bfloat16(f);   // RNE
    return *reinterpret_cast<u16*>(&h);
}
__device__ __forceinline__ u32 packbf(float x, float y) {
    return (u32)f2bf(x) | ((u32)f2bf(y) << 16);
}

template<bool BF16>
__device__ __forceinline__ float ldf(const void* p, int i) {
    if constexpr (BF16) return bf1(((const u16*)p)[i]);
    else                return ((const float*)p)[i];
}

// ---------------------------------------------------------------------------
// Sniffer: flags[0]=1 if float tensors are bf16; flags[1]=1 if edge_index int64.
// ---------------------------------------------------------------------------
__global__ __launch_bounds__(64) void sniff_kernel(const u32* __restrict__ x0w,
                                                   const int* __restrict__ eiw,
                                                   int* __restrict__ flags) {
    int l = threadIdx.x;
    u32 w = x0w[l];
    u32 ef = (w >> 7) & 0xFF;
    bool inr = (ef >= 99 && ef <= 141);
    unsigned long long m1 = __ballot(inr);
    bool zodd = (eiw[2 * l + 1] == 0);
    unsigned long long m2 = __ballot(zodd);
    if (l == 0) {
        flags[0] = (__popcll(m1) >= 48) ? 1 : 0;
        flags[1] = (__popcll(m2) >= 32) ? 1 : 0;
    }
}

// ---------------------------------------------------------------------------
// Projection (unchanged from R3): 256 thr/block, 32 rows/block; thread t:
// group g=t>>7 (0->W1/a1, 1->W2/a2), column c=t&127. W packed bf16 in VGPRs.
// ---------------------------------------------------------------------------
template<bool BF16>
__global__ __launch_bounds__(256) void proj_kernel(
    const void* __restrict__ x0v,
    const void* __restrict__ W1v, const void* __restrict__ b1v,
    const void* __restrict__ W2v, const void* __restrict__ b2v,
    const void* __restrict__ a1wv, const void* __restrict__ a1bv,
    const void* __restrict__ a2wv, const void* __restrict__ a2bv,
    u16* __restrict__ xj, float* __restrict__ a1, float* __restrict__ a2,
    const int* __restrict__ flags, int n)
{
    if ((flags[0] != 0) != BF16) return;      // not our dtype: ghost launch

    __shared__ float xs[32][DIM];
    __shared__ float red[2][2][32];

    const int t   = threadIdx.x;
    const int c   = t & 127;
    const int grp = t >> 7;
    const int r0  = blockIdx.x * 32;
    const int rows = min(32, n - r0);

    const void* Wv  = grp ? W2v  : W1v;
    const void* bv  = grp ? b2v  : b1v;
    const void* awv = grp ? a2wv : a1wv;

    u32 wr[64];
    if constexpr (BF16) {
        const u32* p = (const u32*)Wv + (size_t)c * 64;
        #pragma unroll
        for (int i = 0; i < 64; ++i) wr[i] = p[i];
    } else {
        const float2* p = (const float2*)Wv + (size_t)c * 64;
        #pragma unroll
        for (int i = 0; i < 64; ++i) { float2 v = p[i]; wr[i] = packbf(v.x, v.y); }
    }

    if constexpr (BF16) {
        const u32* xp = (const u32*)x0v + (size_t)r0 * 64;
        int npairs = rows * 64;
        for (int j = t; j < npairs; j += 256) {
            float2 v = bfpair(xp[j]);
            int rr = j >> 6, cp = (j & 63) * 2;
            xs[rr][cp] = v.x; xs[rr][cp + 1] = v.y;
        }
    } else {
        const float* xp = (const float*)x0v + (size_t)r0 * DIM;
        int nel = rows * DIM;
        for (int j = t; j < nel; j += 256) xs[j >> 7][j & 127] = xp[j];
    }
    __syncthreads();

    const float bc  = ldf<BF16>(bv, c);
    const float awc = ldf<BF16>(awv, c);
    const int wv_ = (t >> 6) & 1;

    for (int r = 0; r < rows; ++r) {
        float acc = bc;
        const float2* xr = reinterpret_cast<const float2*>(xs[r]);
        #pragma unroll
        for (int i = 0; i < 64; ++i) {
            float2 xv = xr[i];
            float2 wv2 = bfpair(wr[i]);
            acc = fmaf(xv.x, wv2.x, fmaf(xv.y, wv2.y, acc));
        }
        float v = acc >= 0.f ? acc : 0.2f * acc;   // LeakyReLU(0.2)
        if (grp) xj[(size_t)(r0 + r) * DIM + c] = f2bf(v);
        float p = v * awc;
        #pragma unroll
        for (int off = 32; off > 0; off >>= 1) p += __shfl_down(p, off);
        if ((t & 63) == 0) red[grp][wv_][r] = p;
    }
    __syncthreads();
    if (t < rows)
        a1[r0 + t] = red[0][0][t] + red[0][1][t] + ldf<BF16>(a1bv, 0);
    else if (t >= 128 && t - 128 < rows)
        a2[r0 + t - 128] = red[1][0][t - 128] + red[1][1][t - 128] + ldf<BF16>(a2bv, 0);
}

// ---------------------------------------------------------------------------
// CSR build step 1: degree histogram over src.
// ---------------------------------------------------------------------------
__global__ __launch_bounds__(256) void hist_kernel(
    const int* __restrict__ ei, int* __restrict__ deg,
    const int* __restrict__ flags, int ne)
{
    int i = blockIdx.x * 256 + threadIdx.x;
    if (i >= ne) return;
    int src = flags[1] ? ei[2 * i] : ei[i];
    atomicAdd(&deg[src], 1);
}

// ---------------------------------------------------------------------------
// CSR build step 2: exclusive scan of deg -> ptr, cursor. Single block, 1024.
// ---------------------------------------------------------------------------
__global__ __launch_bounds__(1024) void scan_kernel(
    const int* __restrict__ deg, int* __restrict__ ptr,
    int* __restrict__ cursor, int n)
{
    __shared__ int wsum[16];
    __shared__ int carry;
    const int t = threadIdx.x;
    const int lane = t & 63, w = t >> 6;
    if (t == 0) carry = 0;
    __syncthreads();

    for (int base = 0; base < n; base += 1024) {
        int i = base + t;
        int d = (i < n) ? deg[i] : 0;
        int s = d;                                  // inclusive wave scan
        #pragma unroll
        for (int off = 1; off < 64; off <<= 1) {
            int v = __shfl_up(s, off);
            if (lane >= off) s += v;
        }
        if (lane == 63) wsum[w] = s;
        __syncthreads();                            // B1
        if (w == 0) {
            int v = (lane < 16) ? wsum[lane] : 0;
            #pragma unroll
            for (int off = 1; off < 16; off <<= 1) {
                int u = __shfl_up(v, off);
                if (lane >= off) v += u;
            }
            if (lane < 16) wsum[lane] = v;          // inclusive
        }
        __syncthreads();                            // B2
        int wbase = (w > 0) ? wsum[w - 1] : 0;
        int excl = carry + wbase + (s - d);
        if (i < n) { ptr[i] = excl; cursor[i] = excl; }
        __syncthreads();                            // B3 (carry/wsum consumed)
        if (t == 0) carry += wsum[15];
        __syncthreads();                            // B4 (carry updated)
    }
    if (t == 0) ptr[n] = carry;                     // == ne
}

// ---------------------------------------------------------------------------
// CSR build step 3: scatter edges into src-sorted order; precompute att.
// Record = { dst, att_bits } (8 B).
// ---------------------------------------------------------------------------
__global__ __launch_bounds__(256) void scatter_kernel(
    const int* __restrict__ ei, const float* __restrict__ a1,
    const float* __restrict__ a2, int* __restrict__ cursor,
    uint2* __restrict__ sorted, const int* __restrict__ flags, int ne)
{
    int i = blockIdx.x * 256 + threadIdx.x;
    if (i >= ne) return;
    int src, dst;
    if (flags[1]) { src = ei[2 * i]; dst = ei[2 * (ne + i)]; }
    else          { src = ei[i];     dst = ei[ne + i];       }
    float av  = a1[src] + a2[dst];
    float att = 1.0f / (1.0f + __expf(-av));
    int pos = atomicAdd(&cursor[src], 1);
    uint2 rec; rec.x = (u32)dst; rec.y = __float_as_uint(att);
    sorted[pos] = rec;
}

// ---------------------------------------------------------------------------
// Gather: one wave per src node. Lane l owns cols 2l,2l+1 (fp32 regs).
// acc = x0[src] + sum_k att_k * xj[dst_k];  write out directly (no atomics,
// no acc buffer, no final kernel).
// ---------------------------------------------------------------------------
template<bool BF16>
__global__ __launch_bounds__(256) void gather_kernel(
    const int* __restrict__ ptr, const uint2* __restrict__ sorted,
    const u32* __restrict__ xjw, const void* __restrict__ x0v,
    void* __restrict__ outv, const int* __restrict__ flags, int n)
{
    if ((flags[0] != 0) != BF16) return;
    int s = blockIdx.x * 4 + (threadIdx.x >> 6);
    int l = threadIdx.x & 63;
    if (s >= n) return;

    float2 acc;
    if constexpr (BF16) acc = bfpair(((const u32*)x0v)[(size_t)s * 64 + l]);
    else                acc = ((const float2*)x0v)[(size_t)s * 64 + l];

    int k = ptr[s], end = ptr[s + 1];
    uint2 rec;
    if (k < end) rec = sorted[k];
    for (; k < end; ++k) {
        uint2 cur = rec;
        if (k + 1 < end) rec = sorted[k + 1];       // prefetch next record
        float att = __uint_as_float(cur.y);
        float2 xv = bfpair(xjw[(size_t)cur.x * 64 + l]);
        acc.x = fmaf(att, xv.x, acc.x);
        acc.y = fmaf(att, xv.y, acc.y);
    }

    if constexpr (BF16) ((u32*)outv)[(size_t)s * 64 + l] = packbf(acc.x, acc.y);
    else                ((float2*)outv)[(size_t)s * 64 + l] = acc;
}

extern "C" void kernel_launch(void* const* d_in, const int* in_sizes, int n_in,
                              void* d_out, int out_size, void* d_ws, size_t ws_size,
                              hipStream_t stream)
{
    const void* x0  = d_in[0];
    /* d_in[1] = x1: unused by the reference computation */
    const int*  ei  = (const int*)d_in[2];
    const void* W1  = d_in[3];
    const void* b1  = d_in[4];
    const void* W2  = d_in[5];
    const void* b2  = d_in[6];
    const void* a1w = d_in[7];
    const void* a1b = d_in[8];
    const void* a2w = d_in[9];
    const void* a2b = d_in[10];

    const int n = in_sizes[0] / DIM;        // 50000
    const int e = in_sizes[2] / 2;          // 800000

    // ws: flags | xj bf16 | a1 | a2 | deg | ptr | cursor | sorted(uint2)
    char* ws = (char*)d_ws;
    int* flags = (int*)ws;
    size_t off = 256;
    u16* xj = (u16*)(ws + off);
    off += (size_t)n * DIM * sizeof(u16);   off = (off + 255) & ~(size_t)255;
    float* a1 = (float*)(ws + off);
    off += (size_t)n * sizeof(float);       off = (off + 255) & ~(size_t)255;
    float* a2 = (float*)(ws + off);
    off += (size_t)n * sizeof(float);       off = (off + 255) & ~(size_t)255;
    int* deg = (int*)(ws + off);
    off += (size_t)n * sizeof(int);         off = (off + 255) & ~(size_t)255;
    int* ptr = (int*)(ws + off);
    off += (size_t)(n + 1) * sizeof(int);   off = (off + 255) & ~(size_t)255;
    int* cursor = (int*)(ws + off);
    off += (size_t)n * sizeof(int);         off = (off + 255) & ~(size_t)255;
    uint2* sorted = (uint2*)(ws + off);

    hipMemsetAsync(deg, 0, (size_t)n * sizeof(int), stream);
    sniff_kernel<<<1, 64, 0, stream>>>((const u32*)x0, ei, flags);

    int pblocks = (n + 31) / 32;
    proj_kernel<true ><<<pblocks, 256, 0, stream>>>(x0, W1, b1, W2, b2, a1w, a1b, a2w, a2b, xj, a1, a2, flags, n);
    proj_kernel<false><<<pblocks, 256, 0, stream>>>(x0, W1, b1, W2, b2, a1w, a1b, a2w, a2b, xj, a1, a2, flags, n);

    int eblocks = (e + 255) / 256;
    hist_kernel<<<eblocks, 256, 0, stream>>>(ei, deg, flags, e);
    scan_kernel<<<1, 1024, 0, stream>>>(deg, ptr, cursor, n);
    scatter_kernel<<<eblocks, 256, 0, stream>>>(ei, a1, a2, cursor, sorted, flags, e);

    int gblocks = (n + 3) / 4;
    gather_kernel<true ><<<gblocks, 256, 0, stream>>>(ptr, sorted, (const u32*)xj, x0, d_out, flags, n);
    gather_kernel<false><<<gblocks, 256, 0, stream>>>(ptr, sorted, (const u32*)xj, x0, d_out, flags, n);
}

// Round 5
// 300.505 us; speedup vs baseline: 3.4163x; 1.3501x over previous
//
#include <hip/hip_runtime.h>
#include <hip/hip_bf16.h>

typedef unsigned int u32;
typedef unsigned short u16;

#define DIM 128

typedef __bf16 bfrag __attribute__((ext_vector_type(8)));   // MFMA A/B frag (4 VGPRs)
typedef float  facc  __attribute__((ext_vector_type(4)));   // MFMA C/D frag

__device__ __forceinline__ float2 bfpair(u32 u) {
    union { u32 i; float f; } lo, hi;
    lo.i = (u & 0xFFFFu) << 16;
    hi.i = u & 0xFFFF0000u;
    return make_float2(lo.f, hi.f);
}
__device__ __forceinline__ float bf1(u16 h) {
    union { u32 i; float f; } a; a.i = ((u32)h) << 16; return a.f;
}
__device__ __forceinline__ u16 f2bf(float f) {
    __hip_bfloat16 h = __float2bfloat16(f);   // RNE
    return *reinterpret_cast<u16*>(&h);
}
__device__ __forceinline__ u32 packbf(float x, float y) {
    return (u32)f2bf(x) | ((u32)f2bf(y) << 16);
}

template<bool BF16>
__device__ __forceinline__ float ldf(const void* p, int i) {
    if constexpr (BF16) return bf1(((const u16*)p)[i]);
    else                return ((const float*)p)[i];
}

// load an 8-element bf16 fragment from row-major [*,128] matrix
template<bool BF16>
__device__ __forceinline__ bfrag ldfrag(const void* base, int row, int elt) {
    if constexpr (BF16) {
        const uint4* p = (const uint4*)((const u16*)base + (size_t)row * DIM + elt);
        return __builtin_bit_cast(bfrag, *p);
    } else {
        const float4* p = (const float4*)((const float*)base + (size_t)row * DIM + elt);
        float4 f0 = p[0], f1 = p[1];
        uint4 u = make_uint4(packbf(f0.x, f0.y), packbf(f0.z, f0.w),
                             packbf(f1.x, f1.y), packbf(f1.z, f1.w));
        return __builtin_bit_cast(bfrag, u);
    }
}

// ---------------------------------------------------------------------------
// Sniffer: flags[0]=1 if float tensors are bf16; flags[1]=1 if edge_index int64.
// ---------------------------------------------------------------------------
__global__ __launch_bounds__(64) void sniff_kernel(const u32* __restrict__ x0w,
                                                   const int* __restrict__ eiw,
                                                   int* __restrict__ flags) {
    int l = threadIdx.x;
    u32 w = x0w[l];
    u32 ef = (w >> 7) & 0xFF;
    bool inr = (ef >= 99 && ef <= 141);
    unsigned long long m1 = __ballot(inr);
    bool zodd = (eiw[2 * l + 1] == 0);
    unsigned long long m2 = __ballot(zodd);
    if (l == 0) {
        flags[0] = (__popcll(m1) >= 48) ? 1 : 0;
        flags[1] = (__popcll(m2) >= 32) ? 1 : 0;
    }
}

// ---------------------------------------------------------------------------
// MFMA projection. One wave = 32 rows x ONE matrix (grp: 0->W1/a1, 1->W2/a2),
// all 128 out-cols. A/B frags are 8 contiguous bf16 -> direct 16B global
// loads; no LDS, no barriers. C layout: col=lane&15, row=(lane>>4)*4+reg.
// ---------------------------------------------------------------------------
template<bool BF16>
__global__ __launch_bounds__(256) void proj_kernel(
    const void* __restrict__ x0v,
    const void* __restrict__ W1v, const void* __restrict__ b1v,
    const void* __restrict__ W2v, const void* __restrict__ b2v,
    const void* __restrict__ a1wv, const void* __restrict__ a1bv,
    const void* __restrict__ a2wv, const void* __restrict__ a2bv,
    u16* __restrict__ xj, float* __restrict__ a1, float* __restrict__ a2,
    const int* __restrict__ flags, int n)
{
    if ((flags[0] != 0) != BF16) return;      // not our dtype: ghost launch

    const int wid = threadIdx.x >> 6, l = threadIdx.x & 63;
    const int nchunk = (n + 31) / 32;
    const int job = blockIdx.x * 4 + wid;
    if (job >= 2 * nchunk) return;
    const int grp = job & 1;                  // 0: W1 path, 1: W2 path
    const int r0  = (job >> 1) * 32;

    const void* Wv  = grp ? W2v  : W1v;
    const void* bv  = grp ? b2v  : b1v;
    const void* awv = grp ? a2wv : a1wv;
    const void* abv = grp ? a2bv : a1bv;
    float* aout     = grp ? a2   : a1;

    const int lr = l & 15;                    // A row / B col within tile
    const int q  = l >> 4;                    // quad -> k slice, C row group

    // A fragments: 2 row-tiles x 4 k-slices
    bfrag a[2][4];
    #pragma unroll
    for (int rt = 0; rt < 2; ++rt) {
        int row = r0 + rt * 16 + lr;
        row = min(row, n - 1);                // clamp (stores are guarded)
        #pragma unroll
        for (int k = 0; k < 4; ++k)
            a[rt][k] = ldfrag<BF16>(x0v, row, k * 32 + q * 8);
    }

    facc acc[2][8];
    #pragma unroll
    for (int rt = 0; rt < 2; ++rt)
        #pragma unroll
        for (int ct = 0; ct < 8; ++ct)
            acc[rt][ct] = (facc){0.f, 0.f, 0.f, 0.f};

    #pragma unroll
    for (int ct = 0; ct < 8; ++ct) {
        bfrag b[4];
        #pragma unroll
        for (int k = 0; k < 4; ++k)
            b[k] = ldfrag<BF16>(Wv, ct * 16 + lr, k * 32 + q * 8);
        #pragma unroll
        for (int rt = 0; rt < 2; ++rt)
            #pragma unroll
            for (int k = 0; k < 4; ++k)
                acc[rt][ct] = __builtin_amdgcn_mfma_f32_16x16x32_bf16(
                    a[rt][k], b[k], acc[rt][ct], 0, 0, 0);
    }

    // epilogue: bias + LeakyReLU; store xj (grp==1); dot with a-vector
    float s[2][4] = {{0.f,0.f,0.f,0.f},{0.f,0.f,0.f,0.f}};
    #pragma unroll
    for (int ct = 0; ct < 8; ++ct) {
        float bc  = ldf<BF16>(bv,  ct * 16 + lr);
        float awc = ldf<BF16>(awv, ct * 16 + lr);
        #pragma unroll
        for (int rt = 0; rt < 2; ++rt)
            #pragma unroll
            for (int reg = 0; reg < 4; ++reg) {
                float v = acc[rt][ct][reg] + bc;
                v = v >= 0.f ? v : 0.2f * v;          // LeakyReLU(0.2)
                int row = r0 + rt * 16 + q * 4 + reg;
                if (grp && row < n)
                    xj[(size_t)row * DIM + ct * 16 + lr] = f2bf(v);
                s[rt][reg] = fmaf(v, awc, s[rt][reg]);
            }
    }
    // reduce over the 16 col-lanes (xor masks stay within the quad group)
    #pragma unroll
    for (int off = 1; off < 16; off <<= 1)
        #pragma unroll
        for (int rt = 0; rt < 2; ++rt)
            #pragma unroll
            for (int reg = 0; reg < 4; ++reg)
                s[rt][reg] += __shfl_xor(s[rt][reg], off);
    if (lr == 0) {
        float ab = ldf<BF16>(abv, 0);
        #pragma unroll
        for (int rt = 0; rt < 2; ++rt)
            #pragma unroll
            for (int reg = 0; reg < 4; ++reg) {
                int row = r0 + rt * 16 + q * 4 + reg;
                if (row < n) aout[row] = s[rt][reg] + ab;
            }
    }
}

// ---------------------------------------------------------------------------
// CSR build step 1: degree histogram over src.
// ---------------------------------------------------------------------------
__global__ __launch_bounds__(256) void hist_kernel(
    const int* __restrict__ ei, int* __restrict__ deg,
    const int* __restrict__ flags, int ne)
{
    int i = blockIdx.x * 256 + threadIdx.x;
    if (i >= ne) return;
    int src = flags[1] ? ei[2 * i] : ei[i];
    atomicAdd(&deg[src], 1);
}

// ---------------------------------------------------------------------------
// Parallel scan, 3 phases. A: block-local exclusive scan (1024 elts/block,
// 256 thr x int4) + block sums. B: one wave scans block sums. C: add offsets.
// ---------------------------------------------------------------------------
__global__ __launch_bounds__(256) void scanA_kernel(
    const int* __restrict__ deg, int* __restrict__ ptr,
    int* __restrict__ bsum, int n)
{
    __shared__ int wsums[4];
    const int t = threadIdx.x, lane = t & 63, w = t >> 6;
    const int i = blockIdx.x * 1024 + t * 4;

    int4 d = make_int4(0, 0, 0, 0);
    if (i < n) d = *(const int4*)(deg + i);      // n % 4 == 0
    int ts = d.x + d.y + d.z + d.w;
    int sc = ts;
    #pragma unroll
    for (int off = 1; off < 64; off <<= 1) {
        int v = __shfl_up(sc, off);
        if (lane >= off) sc += v;
    }
    if (lane == 63) wsums[w] = sc;
    __syncthreads();
    int wb = 0;
    #pragma unroll
    for (int j = 0; j < 4; ++j) if (j < w) wb += wsums[j];
    int excl = wb + sc - ts;
    if (i < n) {
        int4 o;
        o.x = excl; o.y = o.x + d.x; o.z = o.y + d.y; o.w = o.z + d.z;
        *(int4*)(ptr + i) = o;
    }
    if (t == 0) bsum[blockIdx.x] = wsums[0] + wsums[1] + wsums[2] + wsums[3];
}

__global__ __launch_bounds__(64) void scanB_kernel(
    int* __restrict__ bsum, int* __restrict__ ptr, int nblk, int n)
{
    int l = threadIdx.x;
    int v = (l < nblk) ? bsum[l] : 0;
    int s = v;
    #pragma unroll
    for (int off = 1; off < 64; off <<= 1) {
        int u = __shfl_up(s, off);
        if (l >= off) s += u;
    }
    if (l < nblk) bsum[l] = s - v;               // exclusive offsets
    if (l == 63) ptr[n] = s;                      // grand total == ne
}

__global__ __launch_bounds__(256) void scanC_kernel(
    int* __restrict__ ptr, int* __restrict__ cursor,
    const int* __restrict__ bsum, int n)
{
    const int i = blockIdx.x * 1024 + threadIdx.x * 4;
    if (i >= n) return;
    int off = bsum[blockIdx.x];
    int4 v = *(const int4*)(ptr + i);
    v.x += off; v.y += off; v.z += off; v.w += off;
    *(int4*)(ptr + i) = v;
    *(int4*)(cursor + i) = v;
}

// ---------------------------------------------------------------------------
// CSR build step 3: scatter edges into src-sorted order; precompute att.
// Record = { dst, att_bits } (8 B).
// ---------------------------------------------------------------------------
__global__ __launch_bounds__(256) void scatter_kernel(
    const int* __restrict__ ei, const float* __restrict__ a1,
    const float* __restrict__ a2, int* __restrict__ cursor,
    uint2* __restrict__ sorted, const int* __restrict__ flags, int ne)
{
    int i = blockIdx.x * 256 + threadIdx.x;
    if (i >= ne) return;
    int src, dst;
    if (flags[1]) { src = ei[2 * i]; dst = ei[2 * (ne + i)]; }
    else          { src = ei[i];     dst = ei[ne + i];       }
    float av  = a1[src] + a2[dst];
    float att = 1.0f / (1.0f + __expf(-av));
    int pos = atomicAdd(&cursor[src], 1);
    uint2 rec; rec.x = (u32)dst; rec.y = __float_as_uint(att);
    sorted[pos] = rec;
}

// ---------------------------------------------------------------------------
// Gather: one wave per src node. Lane l owns cols 2l,2l+1 (fp32 regs).
// out = x0[src] + sum_k att_k * xj[dst_k]; no atomics.
// ---------------------------------------------------------------------------
template<bool BF16>
__global__ __launch_bounds__(256) void gather_kernel(
    const int* __restrict__ ptr, const uint2* __restrict__ sorted,
    const u32* __restrict__ xjw, const void* __restrict__ x0v,
    void* __restrict__ outv, const int* __restrict__ flags, int n)
{
    if ((flags[0] != 0) != BF16) return;
    int s = blockIdx.x * 4 + (threadIdx.x >> 6);
    int l = threadIdx.x & 63;
    if (s >= n) return;

    float2 acc;
    if constexpr (BF16) acc = bfpair(((const u32*)x0v)[(size_t)s * 64 + l]);
    else                acc = ((const float2*)x0v)[(size_t)s * 64 + l];

    int k = ptr[s], end = ptr[s + 1];
    uint2 rec;
    if (k < end) rec = sorted[k];
    for (; k < end; ++k) {
        uint2 cur = rec;
        if (k + 1 < end) rec = sorted[k + 1];       // prefetch next record
        float att = __uint_as_float(cur.y);
        float2 xv = bfpair(xjw[(size_t)cur.x * 64 + l]);
        acc.x = fmaf(att, xv.x, acc.x);
        acc.y = fmaf(att, xv.y, acc.y);
    }

    if constexpr (BF16) ((u32*)outv)[(size_t)s * 64 + l] = packbf(acc.x, acc.y);
    else                ((float2*)outv)[(size_t)s * 64 + l] = acc;
}

extern "C" void kernel_launch(void* const* d_in, const int* in_sizes, int n_in,
                              void* d_out, int out_size, void* d_ws, size_t ws_size,
                              hipStream_t stream)
{
    const void* x0  = d_in[0];
    /* d_in[1] = x1: unused by the reference computation */
    const int*  ei  = (const int*)d_in[2];
    const void* W1  = d_in[3];
    const void* b1  = d_in[4];
    const void* W2  = d_in[5];
    const void* b2  = d_in[6];
    const void* a1w = d_in[7];
    const void* a1b = d_in[8];
    const void* a2w = d_in[9];
    const void* a2b = d_in[10];

    const int n = in_sizes[0] / DIM;        // 50000
    const int e = in_sizes[2] / 2;          // 800000

    // ws: flags | bsum | xj bf16 | a1 | a2 | deg | ptr | cursor | sorted
    char* ws = (char*)d_ws;
    int* flags = (int*)ws;
    int* bsum  = (int*)(ws + 256);          // up to 64 block sums
    size_t off = 1024;
    u16* xj = (u16*)(ws + off);
    off += (size_t)n * DIM * sizeof(u16);   off = (off + 255) & ~(size_t)255;
    float* a1 = (float*)(ws + off);
    off += (size_t)n * sizeof(float);       off = (off + 255) & ~(size_t)255;
    float* a2 = (float*)(ws + off);
    off += (size_t)n * sizeof(float);       off = (off + 255) & ~(size_t)255;
    int* deg = (int*)(ws + off);
    off += (size_t)n * sizeof(int);         off = (off + 255) & ~(size_t)255;
    int* ptr = (int*)(ws + off);
    off += (size_t)(n + 1) * sizeof(int);   off = (off + 255) & ~(size_t)255;
    int* cursor = (int*)(ws + off);
    off += (size_t)n * sizeof(int);         off = (off + 255) & ~(size_t)255;
    uint2* sorted = (uint2*)(ws + off);

    hipMemsetAsync(deg, 0, (size_t)n * sizeof(int), stream);
    sniff_kernel<<<1, 64, 0, stream>>>((const u32*)x0, ei, flags);

    const int nchunk = (n + 31) / 32;
    const int pblocks = (2 * nchunk + 3) / 4;
    proj_kernel<true ><<<pblocks, 256, 0, stream>>>(x0, W1, b1, W2, b2, a1w, a1b, a2w, a2b, xj, a1, a2, flags, n);
    proj_kernel<false><<<pblocks, 256, 0, stream>>>(x0, W1, b1, W2, b2, a1w, a1b, a2w, a2b, xj, a1, a2, flags, n);

    int eblocks = (e + 255) / 256;
    hist_kernel<<<eblocks, 256, 0, stream>>>(ei, deg, flags, e);
    int sblocks = (n + 1023) / 1024;
    scanA_kernel<<<sblocks, 256, 0, stream>>>(deg, ptr, bsum, n);
    scanB_kernel<<<1, 64, 0, stream>>>(bsum, ptr, sblocks, n);
    scanC_kernel<<<sblocks, 256, 0, stream>>>(ptr, cursor, bsum, n);
    scatter_kernel<<<eblocks, 256, 0, stream>>>(ei, a1, a2, cursor, sorted, flags, e);

    int gblocks = (n + 3) / 4;
    gather_kernel<true ><<<gblocks, 256, 0, stream>>>(ptr, sorted, (const u32*)xj, x0, d_out, flags, n);
    gather_kernel<false><<<gblocks, 256, 0, stream>>>(ptr, sorted, (const u32*)xj, x0, d_out, flags, n);
}

// Round 9
// 278.246 us; speedup vs baseline: 3.6896x; 1.0800x over previous
//
#include <hip/hip_runtime.h>
#include <hip/hip_bf16.h>

typedef unsigned int u32;
typedef unsigned short u16;

#define DIM 128
#define LWS 136   // LDS row stride in u16 (128 + 8 pad = 272 B, 16B-aligned)

typedef __bf16 bfrag __attribute__((ext_vector_type(8)));   // MFMA A/B frag (4 VGPRs)
typedef float  facc  __attribute__((ext_vector_type(4)));   // MFMA C/D frag

__device__ __forceinline__ float2 bfpair(u32 u) {
    union { u32 i; float f; } lo, hi;
    lo.i = (u & 0xFFFFu) << 16;
    hi.i = u & 0xFFFF0000u;
    return make_float2(lo.f, hi.f);
}
__device__ __forceinline__ float bf1(u16 h) {
    union { u32 i; float f; } a; a.i = ((u32)h) << 16; return a.f;
}
__device__ __forceinline__ u16 f2bf(float f) {
    __hip_bfloat16 h = __float2bfloat16(f);   // RNE
    return *reinterpret_cast<u16*>(&h);
}
__device__ __forceinline__ u32 packbf(float x, float y) {
    return (u32)f2bf(x) | ((u32)f2bf(y) << 16);
}

template<bool BF16>
__device__ __forceinline__ float ldf(const void* p, int i) {
    if constexpr (BF16) return bf1(((const u16*)p)[i]);
    else                return ((const float*)p)[i];
}

// load an 8-element bf16 fragment from row-major [*,128] matrix (proven R2-R5)
template<bool BF16>
__device__ __forceinline__ bfrag ldfrag(const void* base, int row, int elt) {
    if constexpr (BF16) {
        const uint4* p = (const uint4*)((const u16*)base + (size_t)row * DIM + elt);
        return __builtin_bit_cast(bfrag, *p);
    } else {
        const float4* p = (const float4*)((const float*)base + (size_t)row * DIM + elt);
        float4 f0 = p[0], f1 = p[1];
        uint4 u = make_uint4(packbf(f0.x, f0.y), packbf(f0.z, f0.w),
                             packbf(f1.x, f1.y), packbf(f1.z, f1.w));
        return __builtin_bit_cast(bfrag, u);
    }
}

// ---------------------------------------------------------------------------
// Sniffer (R2-proven): flags[0]=1 if float tensors are bf16; flags[1]=1 if
// edge_index is int64 layout.
// ---------------------------------------------------------------------------
__global__ __launch_bounds__(64) void sniff_kernel(const u32* __restrict__ x0w,
                                                   const int* __restrict__ eiw,
                                                   int* __restrict__ flags) {
    int l = threadIdx.x;
    u32 w = x0w[l];
    u32 ef = (w >> 7) & 0xFF;                 // exponent of low halfword if bf16
    bool inr = (ef >= 99 && ef <= 141);
    unsigned long long m1 = __ballot(inr);
    bool zodd = (eiw[2 * l + 1] == 0);
    unsigned long long m2 = __ballot(zodd);
    if (l == 0) {
        flags[0] = (__popcll(m1) >= 48) ? 1 : 0;
        flags[1] = (__popcll(m2) >= 32) ? 1 : 0;
    }
}

// ---------------------------------------------------------------------------
// MFMA projection, R4-submission-proven math (A=x, B=W, proven C-layout &
// epilogue) + LDS-staged W (converted to bf16 at staging time; bit-identical
// values to the proven ldfrag path). One block = one matrix (grp), 4 chunks.
// ---------------------------------------------------------------------------
template<bool BF16>
__global__ __launch_bounds__(256) void proj_kernel(
    const void* __restrict__ x0v,
    const void* __restrict__ W1v, const void* __restrict__ b1v,
    const void* __restrict__ W2v, const void* __restrict__ b2v,
    const void* __restrict__ a1wv, const void* __restrict__ a1bv,
    const void* __restrict__ a2wv, const void* __restrict__ a2bv,
    u16* __restrict__ xj, float* __restrict__ a1, float* __restrict__ a2,
    const int* __restrict__ flags, int n, int nchunk, int bpg)
{
    if ((flags[0] != 0) != BF16) return;      // wrong dtype: ghost launch
    __shared__ u16 lw[128 * LWS];             // ~34 KB

    const int t   = threadIdx.x;
    const int grp = blockIdx.x / bpg;         // 0: W1/a1, 1: W2/a2
    const int cb  = blockIdx.x % bpg;

    const void* Wv  = grp ? W2v  : W1v;
    const void* bv  = grp ? b2v  : b1v;
    const void* awv = grp ? a2wv : a1wv;
    const void* abv = grp ? a2bv : a1bv;
    float* aout     = grp ? a2   : a1;

    // stage W -> LDS as bf16 (16B chunks, padded rows)
    for (int j = t; j < 2048; j += 256) {
        int r = j >> 4, c = j & 15;
        uint4 u;
        if constexpr (BF16) {
            u = *(const uint4*)((const u16*)Wv + (size_t)r * DIM + c * 8);
        } else {
            const float4* p = (const float4*)((const float*)Wv + (size_t)r * DIM + c * 8);
            float4 f0 = p[0], f1 = p[1];
            u = make_uint4(packbf(f0.x, f0.y), packbf(f0.z, f0.w),
                           packbf(f1.x, f1.y), packbf(f1.z, f1.w));
        }
        *(uint4*)(lw + (size_t)r * LWS + c * 8) = u;
    }
    __syncthreads();

    const int wid = t >> 6, l = t & 63;
    const int chunk = cb * 4 + wid;
    if (chunk >= nchunk) return;
    const int r0 = chunk * 32;
    const int lr = l & 15;                    // A row / B col within tile
    const int q  = l >> 4;                    // quad -> k slice, C row group

    // A fragments = x rows: 2 row-tiles x 4 k-slices (proven)
    bfrag a[2][4];
    #pragma unroll
    for (int rt = 0; rt < 2; ++rt) {
        int row = min(r0 + rt * 16 + lr, n - 1);  // clamp (stores guarded)
        #pragma unroll
        for (int k = 0; k < 4; ++k)
            a[rt][k] = ldfrag<BF16>(x0v, row, k * 32 + q * 8);
    }

    facc acc[2][8];
    #pragma unroll
    for (int rt = 0; rt < 2; ++rt)
        #pragma unroll
        for (int ct = 0; ct < 8; ++ct)
            acc[rt][ct] = (facc){0.f, 0.f, 0.f, 0.f};

    #pragma unroll
    for (int ct = 0; ct < 8; ++ct) {
        bfrag b[4];
        const u16* lrow = lw + (size_t)(ct * 16 + lr) * LWS;
        #pragma unroll
        for (int k = 0; k < 4; ++k)
            b[k] = *(const bfrag*)(lrow + k * 32 + q * 8);
        #pragma unroll
        for (int rt = 0; rt < 2; ++rt)
            #pragma unroll
            for (int k = 0; k < 4; ++k)
                acc[rt][ct] = __builtin_amdgcn_mfma_f32_16x16x32_bf16(
                    a[rt][k], b[k], acc[rt][ct], 0, 0, 0);
    }

    // proven epilogue: bias + LeakyReLU; scalar xj stores; a-dot
    float s[2][4] = {{0.f,0.f,0.f,0.f},{0.f,0.f,0.f,0.f}};
    #pragma unroll
    for (int ct = 0; ct < 8; ++ct) {
        float bc  = ldf<BF16>(bv,  ct * 16 + lr);
        float awc = ldf<BF16>(awv, ct * 16 + lr);
        #pragma unroll
        for (int rt = 0; rt < 2; ++rt)
            #pragma unroll
            for (int reg = 0; reg < 4; ++reg) {
                float v = acc[rt][ct][reg] + bc;
                v = v >= 0.f ? v : 0.2f * v;          // LeakyReLU(0.2)
                int row = r0 + rt * 16 + q * 4 + reg;
                if (grp && row < n)
                    xj[(size_t)row * DIM + ct * 16 + lr] = f2bf(v);
                s[rt][reg] = fmaf(v, awc, s[rt][reg]);
            }
    }
    #pragma unroll
    for (int off = 1; off < 16; off <<= 1)
        #pragma unroll
        for (int rt = 0; rt < 2; ++rt)
            #pragma unroll
            for (int reg = 0; reg < 4; ++reg)
                s[rt][reg] += __shfl_xor(s[rt][reg], off);
    if (lr == 0) {
        float ab = ldf<BF16>(abv, 0);
        #pragma unroll
        for (int rt = 0; rt < 2; ++rt)
            #pragma unroll
            for (int reg = 0; reg < 4; ++reg) {
                int row = r0 + rt * 16 + q * 4 + reg;
                if (row < n) aout[row] = s[rt][reg] + ab;
            }
    }
}

// ---------------------------------------------------------------------------
// CSR step 1: degree histogram over src.
// ---------------------------------------------------------------------------
__global__ __launch_bounds__(256) void hist_kernel(
    const int* __restrict__ ei, int* __restrict__ deg,
    const int* __restrict__ flags, int ne)
{
    int i = blockIdx.x * 256 + threadIdx.x;
    if (i >= ne) return;
    int src = flags[1] ? ei[2 * i] : ei[i];
    atomicAdd(&deg[src], 1);
}

// ---------------------------------------------------------------------------
// Parallel scan (3 phases, proven).
// ---------------------------------------------------------------------------
__global__ __launch_bounds__(256) void scanA_kernel(
    const int* __restrict__ deg, int* __restrict__ ptr,
    int* __restrict__ bsum, int n)
{
    __shared__ int wsums[4];
    const int t = threadIdx.x, lane = t & 63, w = t >> 6;
    const int i = blockIdx.x * 1024 + t * 4;

    int4 d = make_int4(0, 0, 0, 0);
    if (i < n) d = *(const int4*)(deg + i);      // n % 4 == 0
    int ts = d.x + d.y + d.z + d.w;
    int sc = ts;
    #pragma unroll
    for (int off = 1; off < 64; off <<= 1) {
        int v = __shfl_up(sc, off);
        if (lane >= off) sc += v;
    }
    if (lane == 63) wsums[w] = sc;
    __syncthreads();
    int wb = 0;
    #pragma unroll
    for (int j = 0; j < 4; ++j) if (j < w) wb += wsums[j];
    int excl = wb + sc - ts;
    if (i < n) {
        int4 o;
        o.x = excl; o.y = o.x + d.x; o.z = o.y + d.y; o.w = o.z + d.z;
        *(int4*)(ptr + i) = o;
    }
    if (t == 0) bsum[blockIdx.x] = wsums[0] + wsums[1] + wsums[2] + wsums[3];
}

__global__ __launch_bounds__(64) void scanB_kernel(
    int* __restrict__ bsum, int* __restrict__ ptr, int nblk, int n)
{
    int l = threadIdx.x;
    int v = (l < nblk) ? bsum[l] : 0;
    int s = v;
    #pragma unroll
    for (int off = 1; off < 64; off <<= 1) {
        int u = __shfl_up(s, off);
        if (l >= off) s += u;
    }
    if (l < nblk) bsum[l] = s - v;               // exclusive offsets
    if (l == 63) ptr[n] = s;                     // grand total == ne
}

__global__ __launch_bounds__(256) void scanC_kernel(
    int* __restrict__ ptr, int* __restrict__ cursor,
    const int* __restrict__ bsum, int n)
{
    const int i = blockIdx.x * 1024 + threadIdx.x * 4;
    if (i >= n) return;
    int off = bsum[blockIdx.x];
    int4 v = *(const int4*)(ptr + i);
    v.x += off; v.y += off; v.z += off; v.w += off;
    *(int4*)(ptr + i) = v;
    *(int4*)(cursor + i) = v;
}

// ---------------------------------------------------------------------------
// CSR step 3 (proven): scatter {dst, att} into src-sorted order.
// ---------------------------------------------------------------------------
__global__ __launch_bounds__(256) void scatter_kernel(
    const int* __restrict__ ei, const float* __restrict__ a1,
    const float* __restrict__ a2, int* __restrict__ cursor,
    uint2* __restrict__ sorted, const int* __restrict__ flags, int ne)
{
    int i = blockIdx.x * 256 + threadIdx.x;
    if (i >= ne) return;
    int src, dst;
    if (flags[1]) { src = ei[2 * i]; dst = ei[2 * (ne + i)]; }
    else          { src = ei[i];     dst = ei[ne + i];       }
    float av  = a1[src] + a2[dst];
    float att = 1.0f / (1.0f + __expf(-av));
    int pos = atomicAdd(&cursor[src], 1);
    uint2 rec; rec.x = (u32)dst; rec.y = __float_as_uint(att);
    sorted[pos] = rec;
}

// ---------------------------------------------------------------------------
// Gather (proven): one wave per src node, lane l = cols 2l,2l+1.
// out = x0[src] + sum_k att_k * xj[dst_k]; dtype-aware in/out.
// ---------------------------------------------------------------------------
template<bool BF16>
__global__ __launch_bounds__(256) void gather_kernel(
    const int* __restrict__ ptr, const uint2* __restrict__ sorted,
    const u32* __restrict__ xjw, const void* __restrict__ x0v,
    void* __restrict__ outv, const int* __restrict__ flags, int n)
{
    if ((flags[0] != 0) != BF16) return;
    int s = blockIdx.x * 4 + (threadIdx.x >> 6);
    int l = threadIdx.x & 63;
    if (s >= n) return;

    float2 acc;
    if constexpr (BF16) acc = bfpair(((const u32*)x0v)[(size_t)s * 64 + l]);
    else                acc = ((const float2*)x0v)[(size_t)s * 64 + l];

    int k = ptr[s], end = ptr[s + 1];
    uint2 rec;
    if (k < end) rec = sorted[k];
    for (; k < end; ++k) {
        uint2 cur = rec;
        if (k + 1 < end) rec = sorted[k + 1];       // prefetch next record
        float att = __uint_as_float(cur.y);
        float2 xv = bfpair(xjw[(size_t)cur.x * 64 + l]);
        acc.x = fmaf(att, xv.x, acc.x);
        acc.y = fmaf(att, xv.y, acc.y);
    }

    if constexpr (BF16) ((u32*)outv)[(size_t)s * 64 + l] = packbf(acc.x, acc.y);
    else                ((float2*)outv)[(size_t)s * 64 + l] = acc;
}

extern "C" void kernel_launch(void* const* d_in, const int* in_sizes, int n_in,
                              void* d_out, int out_size, void* d_ws, size_t ws_size,
                              hipStream_t stream)
{
    const void* x0  = d_in[0];
    /* d_in[1] = x1: unused by the reference computation */
    const int*  ei  = (const int*)d_in[2];
    const void* W1  = d_in[3];
    const void* b1  = d_in[4];
    const void* W2  = d_in[5];
    const void* b2  = d_in[6];
    const void* a1w = d_in[7];
    const void* a1b = d_in[8];
    const void* a2w = d_in[9];
    const void* a2b = d_in[10];

    const int n = in_sizes[0] / DIM;        // 50000
    const int e = in_sizes[2] / 2;          // 800000

    // ws: flags | bsum | xj bf16 | a1 | a2 | deg | ptr | cursor | sorted(uint2)
    char* ws = (char*)d_ws;
    int* flags = (int*)ws;
    int* bsum  = (int*)(ws + 256);          // up to 192 block sums
    size_t off = 1024;
    u16* xj = (u16*)(ws + off);
    off += (size_t)n * DIM * sizeof(u16);   off = (off + 255) & ~(size_t)255;
    float* a1 = (float*)(ws + off);
    off += (size_t)n * sizeof(float);       off = (off + 255) & ~(size_t)255;
    float* a2 = (float*)(ws + off);
    off += (size_t)n * sizeof(float);       off = (off + 255) & ~(size_t)255;
    int* deg = (int*)(ws + off);
    off += (size_t)n * sizeof(int);         off = (off + 255) & ~(size_t)255;
    int* ptr = (int*)(ws + off);
    off += (size_t)(n + 1) * sizeof(int);   off = (off + 255) & ~(size_t)255;
    int* cursor = (int*)(ws + off);
    off += (size_t)n * sizeof(int);         off = (off + 255) & ~(size_t)255;
    uint2* sorted = (uint2*)(ws + off);

    hipMemsetAsync(deg, 0, (size_t)n * sizeof(int), stream);
    sniff_kernel<<<1, 64, 0, stream>>>((const u32*)x0, ei, flags);

    const int nchunk = (n + 31) / 32;       // 1563
    const int bpg = (nchunk + 3) / 4;       // blocks per matrix
    proj_kernel<true ><<<2 * bpg, 256, 0, stream>>>(x0, W1, b1, W2, b2, a1w, a1b,
                                                    a2w, a2b, xj, a1, a2, flags, n, nchunk, bpg);
    proj_kernel<false><<<2 * bpg, 256, 0, stream>>>(x0, W1, b1, W2, b2, a1w, a1b,
                                                    a2w, a2b, xj, a1, a2, flags, n, nchunk, bpg);

    int eblocks = (e + 255) / 256;
    hist_kernel<<<eblocks, 256, 0, stream>>>(ei, deg, flags, e);
    int sblocks = (n + 1023) / 1024;
    scanA_kernel<<<sblocks, 256, 0, stream>>>(deg, ptr, bsum, n);
    scanB_kernel<<<1, 64, 0, stream>>>(bsum, ptr, sblocks, n);
    scanC_kernel<<<sblocks, 256, 0, stream>>>(ptr, cursor, bsum, n);
    scatter_kernel<<<eblocks, 256, 0, stream>>>(ei, a1, a2, cursor, sorted, flags, e);

    int gblocks = (n + 3) / 4;
    gather_kernel<true ><<<gblocks, 256, 0, stream>>>(ptr, sorted, (const u32*)xj,
                                                      x0, d_out, flags, n);
    gather_kernel<false><<<gblocks, 256, 0, stream>>>(ptr, sorted, (const u32*)xj,
                                                      x0, d_out, flags, n);
}